// Round 6
// baseline (243.402 us; speedup 1.0000x reference)
//
#include <hip/hip_runtime.h>
#include <hip/hip_bf16.h>

typedef __attribute__((ext_vector_type(8))) short short8;
typedef __attribute__((ext_vector_type(4))) float float4v;
typedef unsigned int uint;

#define NBLK 192  // blocks for edge-parallel passes

static __device__ __forceinline__ float2 up_bf2(uint v) {
    float2 r;
    r.x = __uint_as_float(v << 16);
    r.y = __uint_as_float(v & 0xffff0000u);
    return r;
}
static __device__ __forceinline__ short f2bf_bits(float x) {
    union { __hip_bfloat16 h; short s; } u;
    u.h = __float2bfloat16(x);
    return u.s;
}

// ---------------- degree count (+ fused W1/W2 frag prebuild) ----------------
// r25: direct-CSR build.  Per-edge global atomicAdd on deg[] (800k atomics
// over 50k addresses, ~16/addr) + LDS bucket hist -> atomic btot.
// Blocks >= nblk build W1frag (8 blocks) / W2frag (32 blocks) -- off the
// critical path (they only depend on W1/W2 inputs).

__global__ __launch_bounds__(256) void k_deg(const int* __restrict__ dst, int E, int chunk,
        int nbuck, int nblk, int* __restrict__ deg, int* __restrict__ btot,
        const float* __restrict__ W1, const float* __restrict__ W2,
        __hip_bfloat16* __restrict__ W1frag, __hip_bfloat16* __restrict__ W2frag) {
    int blk = blockIdx.x;
    if (blk >= nblk) {
        int xb = blk - nblk;
        if (xb < 8) {  // W1frag role: B-frag 16x16x32, lane holds
                       // B[k=quad*8+j][col=ctile*16+(lane&15)], k>=9 -> 0
            int t = xb * 256 + threadIdx.x;
            if (t < 32 * 64) {
                int ctile = t >> 6, lane = t & 63;
                int col = ctile * 16 + (lane & 15);
                int k0 = (lane >> 4) * 8;
                short8 o;
#pragma unroll
                for (int j = 0; j < 8; ++j) {
                    int k = k0 + j;
                    o[j] = f2bf_bits(k < 9 ? W1[k * 512 + col] : 0.f);
                }
                *reinterpret_cast<short8*>(W1frag + (size_t)t * 8) = o;
            }
        } else {  // W2frag role: W2frag[(kb*128+c)*8+j] = bf16(W2[(kb*8+j)*128+c])
            int t = (xb - 8) * 256 + threadIdx.x;
            if (t < 64 * 128) {
                int kb = t >> 7, c = t & 127;
                const float* wp = W2 + (size_t)(kb * 8) * 128 + c;
                short8 o;
#pragma unroll
                for (int j = 0; j < 8; ++j) o[j] = f2bf_bits(wp[j * 128]);
                *reinterpret_cast<short8*>(W2frag + (size_t)t * 8) = o;
            }
        }
        return;
    }
    __shared__ int h[256];
    int t = threadIdx.x;
    h[t] = 0;
    __syncthreads();
    int e0 = blk * chunk, e1 = min(E, e0 + chunk);
    for (int e = e0 + t; e < e1; e += 256) {
        int d = dst[e];
        atomicAdd(&deg[d], 1);      // global, fire-and-forget
        atomicAdd(&h[d >> 8], 1);   // LDS bucket hist
    }
    __syncthreads();
    if (t < nbuck && h[t]) atomicAdd(&btot[t], h[t]);
}

// ---------------- per-bucket scan: row_ptr/rowcur/dinv/xs ----------------
// Block b handles nodes [b*256,(b+1)*256).  Redundant in-LDS scan of btot
// gives the bucket base; in-LDS scan of the block's 256 deg values gives
// within-bucket offsets.  Replaces btot+bscan+csrbuild's scan half.

__global__ __launch_bounds__(256) void k_scan(const int* __restrict__ deg,
        const int* __restrict__ btot, const float* __restrict__ x,
        int E, int n, int nbuck,
        int* __restrict__ row_ptr, int* __restrict__ rowcur,
        float* __restrict__ dinv, float* __restrict__ xs) {
    __shared__ int s[256], sb[256], cnt[256];
    int b = blockIdx.x, t = threadIdx.x;
    int node = (b << 8) + t;
    int d = (node < n) ? deg[node] : 0;
    cnt[t] = d;
    s[t] = d;
    sb[t] = (t < nbuck) ? btot[t] : 0;
    __syncthreads();
    for (int off = 1; off < 256; off <<= 1) {
        int u = (t >= off) ? s[t - off] : 0;
        int u2 = (t >= off) ? sb[t - off] : 0;
        __syncthreads();
        s[t] += u;
        sb[t] += u2;
        __syncthreads();
    }
    int base = (b > 0) ? sb[b - 1] : 0;        // exclusive prefix of bucket totals
    int myBase = base + s[t] - cnt[t];         // exclusive within-bucket prefix
    if (node < n) {
        row_ptr[node] = myBase;
        rowcur[node] = myBase;
        dinv[node] = rsqrtf((float)(d + 1));   // +1 self-loop
    }
    if (b == nbuck - 1 && t == 0) row_ptr[n] = E;
    int node0 = b << 8;
    int cntNodes = min(n, (b + 1) << 8) - node0;
    for (int j = t; j < cntNodes * 9; j += 256) {
        int nl = j / 9, f = j - nl * 9;
        float dnl = rsqrtf((float)(cnt[nl] + 1));
        xs[(size_t)(node0 + nl) * 9 + f] = dnl * x[(size_t)(node0 + nl) * 9 + f];
    }
}

// ---------------- CSR fill: edge-parallel atomic cursor ----------------
// Within-row order nondeterministic (f32 sum order covered by tolerance);
// no binned intermediate at all.

__global__ __launch_bounds__(256) void k_fill(const int* __restrict__ src,
        const int* __restrict__ dst, int E, int chunk,
        int* __restrict__ rowcur, int* __restrict__ csr) {
    int blk = blockIdx.x, t = threadIdx.x;
    int e0 = blk * chunk, e1 = min(E, e0 + chunk);
    for (int e = e0 + t; e < e1; e += 256) {
        int d = dst[e];
        int pos = atomicAdd(&rowcur[d], 1);
        csr[pos] = src[e];
    }
}

// ---------------- Layer 1 aggregate: aggx_bf = bf16(dinv .* (sum xs)) [node][32] ----------------
// Output padded to K=32 (cols 9..31 zero) in bf16: directly MFMA-A-consumable.

__global__ __launch_bounds__(256) void k_agg1(const float* __restrict__ xs,
                       const float* __restrict__ dinv,
                       const int* __restrict__ row_ptr, const int* __restrict__ csr,
                       __hip_bfloat16* __restrict__ aggx_bf, int n) {
    int node = blockIdx.x * 16 + (threadIdx.x >> 4);
    if (node >= n) return;
    int f = threadIdx.x & 15;
    bool act = f < 9;
    float acc = act ? xs[node * 9 + f] : 0.f;  // self-loop (xs = dinv*x)
    int e0 = row_ptr[node], e1 = row_ptr[node + 1];
    int e = e0;
    for (; e + 4 <= e1; e += 4) {
        int s0 = csr[e], s1 = csr[e + 1], s2 = csr[e + 2], s3 = csr[e + 3];
        float x0 = act ? xs[s0 * 9 + f] : 0.f;
        float x1 = act ? xs[s1 * 9 + f] : 0.f;
        float x2 = act ? xs[s2 * 9 + f] : 0.f;
        float x3 = act ? xs[s3 * 9 + f] : 0.f;
        acc += (x0 + x1) + (x2 + x3);
    }
    for (; e < e1; ++e) {
        int sA = csr[e];
        acc += act ? xs[sA * 9 + f] : 0.f;
    }
    float v = act ? dinv[node] * acc : 0.f;
    __hip_bfloat16* op = aggx_bf + (size_t)node * 32;
    union { __hip_bfloat16 h; short s; } u;
    u.h = __float2bfloat16(v);
    reinterpret_cast<short*>(op)[f] = u.s;
    reinterpret_cast<short*>(op)[16 + f] = 0;
}

// ---------------- Fused layer1-MFMA + layer2 GEMM ----------------
// r23: B-fragments read directly from precomputed W2frag (global, L2-resident);
// no per-block LDS staging of W2 (LDS 20 KB).  r21 pair structure kept.
__global__ __launch_bounds__(512, 2) void k_l12(const __hip_bfloat16* __restrict__ aggx_bf,
                       const __hip_bfloat16* __restrict__ W1frag,
                       const __hip_bfloat16* __restrict__ W2frag,
                       const float* __restrict__ b1,
                       const float* __restrict__ dinv,
                       __hip_bfloat16* __restrict__ t2, int n, int npair) {
    __shared__ short h1s[8][2][16][40];   // 20 KB: per-wave 2 tiles x 16 rows x 32 cols
    int t = threadIdx.x;
    int wid = t >> 6, lane = t & 63;
    int pair = blockIdx.x * 8 + wid;
    if (pair >= npair) return;
    int r = lane & 15, quad = lane >> 4;
    short (*hs0)[40] = h1s[wid][0];
    short (*hs1)[40] = h1s[wid][1];

    int m0 = pair << 5;
    // A-frags for h1-GEMM: aggx_bf[m][quad*8+j] (padded rows OOB-safe)
    short8 aagg0 = *reinterpret_cast<const short8*>(
        aggx_bf + (size_t)(m0 + r) * 32 + quad * 8);
    short8 aagg1 = *reinterpret_cast<const short8*>(
        aggx_bf + (size_t)(m0 + 16 + r) * 32 + quad * 8);

    float4v acc0[8], acc1[8];
#pragma unroll
    for (int cg = 0; cg < 8; ++cg) {
        acc0[cg] = (float4v){0, 0, 0, 0};
        acc1[cg] = (float4v){0, 0, 0, 0};
    }

    for (int kt = 0; kt < 16; ++kt) {
        // h1 cols [kt*32, kt*32+32): two 16-col MFMAs per tile
        short8 bf0 = *reinterpret_cast<const short8*>(
            W1frag + ((size_t)(2 * kt) * 64 + lane) * 8);
        short8 bf1 = *reinterpret_cast<const short8*>(
            W1frag + ((size_t)(2 * kt + 1) * 64 + lane) * 8);
        float4v c00 = __builtin_amdgcn_mfma_f32_16x16x32_bf16(
            aagg0, bf0, (float4v){0, 0, 0, 0}, 0, 0, 0);
        float4v c01 = __builtin_amdgcn_mfma_f32_16x16x32_bf16(
            aagg0, bf1, (float4v){0, 0, 0, 0}, 0, 0, 0);
        float4v c10 = __builtin_amdgcn_mfma_f32_16x16x32_bf16(
            aagg1, bf0, (float4v){0, 0, 0, 0}, 0, 0, 0);
        float4v c11 = __builtin_amdgcn_mfma_f32_16x16x32_bf16(
            aagg1, bf1, (float4v){0, 0, 0, 0}, 0, 0, 0);
        float bb0 = b1[kt * 32 + r];
        float bb1 = b1[kt * 32 + 16 + r];
        // B-frags for the acc-GEMM: direct from global (L2-resident W2frag)
        short8 bfr[8];
#pragma unroll
        for (int cg = 0; cg < 8; ++cg)
            bfr[cg] = *reinterpret_cast<const short8*>(
                W2frag + (size_t)(((kt * 4 + quad) * 128) + cg * 16 + r) * 8);
        // C-layout (col=lane&15, row=quad*4+i) -> LDS [row][col], both tiles
#pragma unroll
        for (int i = 0; i < 4; ++i) {
            int row = quad * 4 + i;
            hs0[row][r]      = f2bf_bits(fmaxf(c00[i] + bb0, 0.f));
            hs0[row][16 + r] = f2bf_bits(fmaxf(c01[i] + bb1, 0.f));
            hs1[row][r]      = f2bf_bits(fmaxf(c10[i] + bb0, 0.f));
            hs1[row][16 + r] = f2bf_bits(fmaxf(c11[i] + bb1, 0.f));
        }
        // same-wave read back in A-layout: A[m=r][k=quad*8+j]
        short8 am0 = *reinterpret_cast<const short8*>(&hs0[r][quad * 8]);
        short8 am1 = *reinterpret_cast<const short8*>(&hs1[r][quad * 8]);
#pragma unroll
        for (int cg = 0; cg < 8; ++cg) {
            acc0[cg] = __builtin_amdgcn_mfma_f32_16x16x32_bf16(am0, bfr[cg], acc0[cg], 0, 0, 0);
            acc1[cg] = __builtin_amdgcn_mfma_f32_16x16x32_bf16(am1, bfr[cg], acc1[cg], 0, 0, 0);
        }
    }

    // Epilogue: C/D col = lane&15, row = quad*4 + reg; scale row by dinv[node]
#pragma unroll
    for (int i = 0; i < 4; ++i) {
        int node0 = m0 + quad * 4 + i;
        if (node0 < n) {
            float di = dinv[node0];
            __hip_bfloat16* op = t2 + (size_t)node0 * 128 + r;
#pragma unroll
            for (int cg = 0; cg < 8; ++cg)
                op[cg * 16] = __float2bfloat16(di * acc0[cg][i]);
        }
        int node1 = m0 + 16 + quad * 4 + i;
        if (node1 < n) {
            float di = dinv[node1];
            __hip_bfloat16* op = t2 + (size_t)node1 * 128 + r;
#pragma unroll
            for (int cg = 0; cg < 8; ++cg)
                op[cg * 16] = __float2bfloat16(di * acc1[cg][i]);
        }
    }
}

// ---------------- Layer 2 aggregate + fused layer-3 matmul ----------------
// r20: uint2 gathers (8 B/lane, 32 lanes/row) with even/odd edge split across
// wave halves -> 16 edges in flight per unrolled iter, half the load instrs.
// shfl_xor(32) merges halves; final reduce is within 32-lane groups only.

__global__ __launch_bounds__(256) void k_agg2(const uint* __restrict__ t2u,
                       const float* __restrict__ dinv,
                       const int* __restrict__ row_ptr, const int* __restrict__ csr,
                       const float* __restrict__ b2, const float* __restrict__ W3,
                       float2* __restrict__ t3, int n) {
    int node = blockIdx.x * 4 + (threadIdx.x >> 6);
    if (node >= n) return;
    int lane = threadIdx.x & 63;
    int half = lane >> 5;    // 0: even edges, 1: odd edges
    int cl = lane & 31;      // channel chunk: channels 4*cl .. 4*cl+3
    const uint2* t2v = reinterpret_cast<const uint2*>(t2u);

    float a0 = 0.f, a1 = 0.f, a2 = 0.f, a3 = 0.f;
    if (half == 0) {  // self row (t2' = dinv*t2), added once
        uint2 sv = t2v[(size_t)node * 32 + cl];
        float2 pa = up_bf2(sv.x), pb = up_bf2(sv.y);
        a0 = pa.x; a1 = pa.y; a2 = pb.x; a3 = pb.y;
    }

    int e0 = row_ptr[node], e1 = row_ptr[node + 1];
    int eb = e0;
    for (; eb + 16 <= e1; eb += 16) {  // 8 edges per half in flight
        int si[8];
        uint2 ri[8];
#pragma unroll
        for (int j = 0; j < 8; ++j) si[j] = csr[eb + half + 2 * j];
#pragma unroll
        for (int j = 0; j < 8; ++j) ri[j] = t2v[(size_t)si[j] * 32 + cl];
#pragma unroll
        for (int j = 0; j < 8; ++j) {
            float2 qa = up_bf2(ri[j].x), qb = up_bf2(ri[j].y);
            a0 += qa.x; a1 += qa.y; a2 += qb.x; a3 += qb.y;
        }
    }
    for (; eb + 4 <= e1; eb += 4) {  // 2 edges per half
        int s0 = csr[eb + half], s1 = csr[eb + half + 2];
        uint2 r0 = t2v[(size_t)s0 * 32 + cl];
        uint2 r1 = t2v[(size_t)s1 * 32 + cl];
        float2 qa = up_bf2(r0.x), qb = up_bf2(r0.y);
        float2 qc = up_bf2(r1.x), qd = up_bf2(r1.y);
        a0 += qa.x + qc.x; a1 += qa.y + qc.y;
        a2 += qb.x + qd.x; a3 += qb.y + qd.y;
    }
    for (int e = eb + half; e < e1; e += 2) {  // tail 0-3 edges
        uint2 rv = t2v[(size_t)csr[e] * 32 + cl];
        float2 qa = up_bf2(rv.x), qb = up_bf2(rv.y);
        a0 += qa.x; a1 += qa.y; a2 += qb.x; a3 += qb.y;
    }

    // merge even/odd halves: lanes l and l^32 hold same channel chunk
    a0 += __shfl_xor(a0, 32);
    a1 += __shfl_xor(a1, 32);
    a2 += __shfl_xor(a2, 32);
    a3 += __shfl_xor(a3, 32);

    float di = dinv[node];
    float4 bb = *reinterpret_cast<const float4*>(b2 + 4 * cl);
    float h0 = fmaxf(di * a0 + bb.x, 0.f);
    float h1v = fmaxf(di * a1 + bb.y, 0.f);
    float h2 = fmaxf(di * a2 + bb.z, 0.f);
    float h3 = fmaxf(di * a3 + bb.w, 0.f);
    float4 wlo = *reinterpret_cast<const float4*>(W3 + 8 * cl);      // rows 4cl, 4cl+1
    float4 whi = *reinterpret_cast<const float4*>(W3 + 8 * cl + 4);  // rows 4cl+2, 4cl+3
    float c0 = h0 * wlo.x + h1v * wlo.z + h2 * whi.x + h3 * whi.z;
    float c1 = h0 * wlo.y + h1v * wlo.w + h2 * whi.y + h3 * whi.w;
#pragma unroll
    for (int off = 16; off; off >>= 1) {  // reduce within each 32-lane group
        c0 += __shfl_xor(c0, off);
        c1 += __shfl_xor(c1, off);
    }
    if (lane == 0) t3[node] = make_float2(di * c0, di * c1);  // prescaled
}

// ---------------- Layer 3 aggregate + log_softmax ----------------

__global__ void k_agg3(const float2* __restrict__ t3, const float* __restrict__ dinv,
                       const int* __restrict__ row_ptr, const int* __restrict__ csr,
                       const float* __restrict__ b3, float2* __restrict__ outv, int n) {
    int node = blockIdx.x * blockDim.x + threadIdx.x;
    if (node >= n) return;
    float2 s = t3[node];  // self (t3' = dinv*t3)
    float a0 = s.x, a1 = s.y;
    int e0 = row_ptr[node], e1 = row_ptr[node + 1];
    int e = e0;
    for (; e + 4 <= e1; e += 4) {
        int s0 = csr[e], s1 = csr[e + 1], s2 = csr[e + 2], s3 = csr[e + 3];
        float2 q0 = t3[s0], q1 = t3[s1], q2 = t3[s2], q3 = t3[s3];
        a0 += q0.x + q1.x + q2.x + q3.x;
        a1 += q0.y + q1.y + q2.y + q3.y;
    }
    for (; e < e1; ++e) {
        float2 q0 = t3[csr[e]];
        a0 += q0.x;
        a1 += q0.y;
    }
    float di = dinv[node];
    float z0 = di * a0 + b3[0];
    float z1 = di * a1 + b3[1];
    float m = fmaxf(z0, z1);
    float lse = m + logf(expf(z0 - m) + expf(z1 - m));
    outv[node] = make_float2(z0 - lse, z1 - lse);
}

// ---------------- launch ----------------

extern "C" void kernel_launch(void* const* d_in, const int* in_sizes, int n_in,
                              void* d_out, int out_size, void* d_ws, size_t ws_size,
                              hipStream_t stream) {
    const float* x  = (const float*)d_in[0];
    const float* W1 = (const float*)d_in[1];
    const float* b1 = (const float*)d_in[2];
    const float* W2 = (const float*)d_in[3];
    const float* b2 = (const float*)d_in[4];
    const float* W3 = (const float*)d_in[5];
    const float* b3 = (const float*)d_in[6];
    const int* edges = (const int*)d_in[7];

    int n = in_sizes[0] / 9;
    int E = in_sizes[7] / 2;
    const int* src = edges;
    const int* dst = edges + E;

    char* p = (char*)d_ws;
    auto alloc = [&](size_t bytes) {
        char* q = p;
        p += (bytes + 511) & ~(size_t)511;
        return q;
    };
    float* dinv       = (float*)alloc((size_t)n * 4);
    int*   row_ptr    = (int*)alloc((size_t)(n + 1) * 4);
    int*   rowcur     = (int*)alloc((size_t)n * 4);
    int*   csr        = (int*)alloc((size_t)E * 4);
    int*   deg        = (int*)alloc((size_t)(n + 256) * 4);  // deg[n] + btot[256] contiguous
    int*   btot       = deg + n;
    float* xs         = (float*)alloc((size_t)n * 9 * 4);
    __hip_bfloat16* aggx_bf = (__hip_bfloat16*)alloc((size_t)(n + 64) * 32 * 2);
    __hip_bfloat16* W1frag  = (__hip_bfloat16*)alloc((size_t)32 * 64 * 8 * 2);
    __hip_bfloat16* W2frag  = (__hip_bfloat16*)alloc((size_t)64 * 128 * 8 * 2);
    __hip_bfloat16* t2 = (__hip_bfloat16*)alloc((size_t)n * 128 * 2);
    float2* t3 = (float2*)alloc((size_t)n * 8);

    const int B = 256;
    int nbuck = ((n - 1) >> 8) + 1;           // 196 for n=50000 (needs <=256)
    int chunk = (E + NBLK - 1) / NBLK;

    hipMemsetAsync(deg, 0, (size_t)(n + 256) * 4, stream);  // deg + btot
    k_deg<<<NBLK + 40, B, 0, stream>>>(dst, E, chunk, nbuck, NBLK,
                                       deg, btot, W1, W2, W1frag, W2frag);
    k_scan<<<nbuck, B, 0, stream>>>(deg, btot, x, E, n, nbuck,
                                    row_ptr, rowcur, dinv, xs);
    k_fill<<<NBLK, B, 0, stream>>>(src, dst, E, chunk, rowcur, csr);

    k_agg1<<<(n + 15) / 16, B, 0, stream>>>(xs, dinv, row_ptr, csr, aggx_bf, n);

    int ntile = (n + 15) / 16;                // 3125
    int npair = (ntile + 1) / 2;              // 1563 wave-tasks (32 rows each)
    k_l12<<<(npair + 7) / 8, 512, 0, stream>>>(aggx_bf, W1frag, W2frag, b1, dinv, t2, n, npair);
    k_agg2<<<(n + 3) / 4, 256, 0, stream>>>((const uint*)t2, dinv, row_ptr, csr, b2, W3, t3, n);

    k_agg3<<<(n + B - 1) / B, B, 0, stream>>>(t3, dinv, row_ptr, csr, b3, (float2*)d_out, n);
}

// Round 7
// 233.743 us; speedup vs baseline: 1.0413x; 1.0413x over previous
//
#include <hip/hip_runtime.h>
#include <hip/hip_bf16.h>

typedef __attribute__((ext_vector_type(8))) short short8;
typedef __attribute__((ext_vector_type(4))) float float4v;
typedef unsigned int uint;

#define NBLK 192  // blocks for hist/scatterbin passes

static __device__ __forceinline__ float2 up_bf2(uint v) {
    float2 r;
    r.x = __uint_as_float(v << 16);
    r.y = __uint_as_float(v & 0xffff0000u);
    return r;
}
static __device__ __forceinline__ short f2bf_bits(float x) {
    union { __hip_bfloat16 h; short s; } u;
    u.h = __float2bfloat16(x);
    return u.s;
}

// ---------------- per-(bucket,block) histogram, LDS only ----------------

__global__ __launch_bounds__(256) void k_hist(const int* __restrict__ dst, int E, int chunk,
        int shift, int nbuck, int* __restrict__ histBlk) {
    __shared__ int h[256];
    h[threadIdx.x] = 0;
    __syncthreads();
    int blk = blockIdx.x;
    int e0 = blk * chunk, e1 = min(E, e0 + chunk);
    for (int e = e0 + threadIdx.x; e < e1; e += 256)
        atomicAdd(&h[dst[e] >> shift], 1);
    __syncthreads();
    if (threadIdx.x < nbuck) histBlk[threadIdx.x * NBLK + blk] = h[threadIdx.x];
}

// ---------------- bucket totals ----------------

__global__ __launch_bounds__(256) void k_btot(const int* __restrict__ histBlk,
                                              int* __restrict__ btot) {
    __shared__ int s[256];
    int b = blockIdx.x, t = threadIdx.x;
    s[t] = (t < NBLK) ? histBlk[b * NBLK + t] : 0;
    __syncthreads();
    for (int off = 128; off; off >>= 1) {
        if (t < off) s[t] += s[t + off];
        __syncthreads();
    }
    if (t == 0) btot[b] = s[0];
}

// ---------------- per-(bucket,block) bases + bucket bases ----------------

__global__ __launch_bounds__(256) void k_bscan(const int* __restrict__ histBlk,
        const int* __restrict__ btot, int nbuck,
        int* __restrict__ baseBlk, int* __restrict__ bucketBase) {
    __shared__ int s[256], sb[256];
    int b = blockIdx.x, t = threadIdx.x;
    int v = (t < NBLK) ? histBlk[b * NBLK + t] : 0;
    s[t] = v;
    sb[t] = (t < nbuck) ? btot[t] : 0;
    __syncthreads();
    for (int off = 1; off < 256; off <<= 1) {
        int u = (t >= off) ? s[t - off] : 0;
        int u2 = (t >= off) ? sb[t - off] : 0;
        __syncthreads();
        s[t] += u;
        sb[t] += u2;
        __syncthreads();
    }
    int base = (b > 0) ? sb[b - 1] : 0;  // exclusive prefix of bucket totals
    if (t < NBLK) baseBlk[b * NBLK + t] = base + s[t] - v;
    if (t == 0) bucketBase[b] = base;
}

// ---------------- scatter into per-(bucket,block) slices, packed payload ----------------
// binned word = src (24b) | dst_local (8b).  Requires n < 2^24 and shift == 8.

__global__ __launch_bounds__(256) void k_scatterbin(const int* __restrict__ src,
        const int* __restrict__ dst, int E, int chunk, int shift, int nbuck,
        const int* __restrict__ baseBlk, uint* __restrict__ binned) {
    __shared__ int cur[256];
    int blk = blockIdx.x;
    if (threadIdx.x < nbuck) cur[threadIdx.x] = baseBlk[threadIdx.x * NBLK + blk];
    __syncthreads();
    int e0 = blk * chunk, e1 = min(E, e0 + chunk);
    int mask = (1 << shift) - 1;
    for (int e = e0 + threadIdx.x; e < e1; e += 256) {
        int d = dst[e];
        int pos = atomicAdd(&cur[d >> shift], 1);
        binned[pos] = (uint)src[e] | ((uint)(d & mask) << 24);
    }
}

// ---------------- per-bucket: counts -> row_ptr/dinv/xs, then exact csr scatter ----------------

__global__ __launch_bounds__(256) void k_csrbuild(const uint* __restrict__ binned,
        const int* __restrict__ bucketBase, const float* __restrict__ x,
        int E, int shift, int n, int nbuck,
        int* __restrict__ row_ptr, float* __restrict__ dinv, float* __restrict__ xs,
        int* __restrict__ csr) {
    __shared__ int cnt[256], lcur[256];
    int b = blockIdx.x, t = threadIdx.x;
    cnt[t] = 0;
    __syncthreads();
    int lo = bucketBase[b];
    int hi = (b + 1 < nbuck) ? bucketBase[b + 1] : E;
    for (int e = lo + t; e < hi; e += 256)
        atomicAdd(&cnt[binned[e] >> 24], 1);
    __syncthreads();
    int c = cnt[t];
    lcur[t] = c;
    __syncthreads();
    for (int off = 1; off < 256; off <<= 1) {
        int u = (t >= off) ? lcur[t - off] : 0;
        __syncthreads();
        lcur[t] += u;
        __syncthreads();
    }
    int node0 = b << shift;
    int nodeEnd = min(n, (b + 1) << shift);
    int cntNodes = nodeEnd - node0;
    int myBase = lo + lcur[t] - c;  // exclusive prefix within bucket
    if (t < cntNodes) {
        row_ptr[node0 + t] = myBase;
        dinv[node0 + t] = rsqrtf((float)(c + 1));  // +1 self-loop
    }
    if (b == nbuck - 1 && t == 0) row_ptr[n] = E;
    for (int j = t; j < cntNodes * 9; j += 256) {
        int nl = j / 9, f = j - nl * 9;
        float dnl = rsqrtf((float)(cnt[nl] + 1));
        xs[(size_t)(node0 + nl) * 9 + f] = dnl * x[(size_t)(node0 + nl) * 9 + f];
    }
    __syncthreads();
    lcur[t] = myBase;  // running cursors
    __syncthreads();
    for (int e = lo + t; e < hi; e += 256) {
        uint p = binned[e];
        int pos = atomicAdd(&lcur[p >> 24], 1);
        csr[pos] = (int)(p & 0xFFFFFF);
    }
}

// ---------------- Layer 1 aggregate (+ fused W1/W2 frag prebuild) ----------------

__global__ __launch_bounds__(256) void k_agg1w(const float* __restrict__ xs,
                       const float* __restrict__ dinv,
                       const int* __restrict__ row_ptr, const int* __restrict__ csr,
                       const float* __restrict__ W1, const float* __restrict__ W2,
                       __hip_bfloat16* __restrict__ aggx_bf,
                       __hip_bfloat16* __restrict__ W1frag,
                       __hip_bfloat16* __restrict__ W2frag, int n, int nagg) {
    int bid = blockIdx.x;
    if (bid >= nagg) {
        int xb = bid - nagg;
        if (xb < 8) {  // W1frag role (8 blocks, 2048 threads)
            int t = xb * 256 + threadIdx.x;
            if (t < 32 * 64) {
                int ctile = t >> 6, lane = t & 63;
                int col = ctile * 16 + (lane & 15);
                int k0 = (lane >> 4) * 8;
                short8 o;
#pragma unroll
                for (int j = 0; j < 8; ++j) {
                    int k = k0 + j;
                    o[j] = f2bf_bits(k < 9 ? W1[k * 512 + col] : 0.f);
                }
                *reinterpret_cast<short8*>(W1frag + (size_t)t * 8) = o;
            }
        } else {  // W2frag role (32 blocks): W2frag[(kb*128+c)*8+j] = bf16(W2[(kb*8+j)*128+c])
            int t = (xb - 8) * 256 + threadIdx.x;
            if (t < 64 * 128) {
                int kb = t >> 7, c = t & 127;
                const float* wp = W2 + (size_t)(kb * 8) * 128 + c;
                short8 o;
#pragma unroll
                for (int j = 0; j < 8; ++j) o[j] = f2bf_bits(wp[j * 128]);
                *reinterpret_cast<short8*>(W2frag + (size_t)t * 8) = o;
            }
        }
        return;
    }
    int node = bid * 16 + (threadIdx.x >> 4);
    if (node >= n) return;
    int f = threadIdx.x & 15;
    bool act = f < 9;
    float acc = act ? xs[node * 9 + f] : 0.f;  // self-loop (xs = dinv*x)
    int e0 = row_ptr[node], e1 = row_ptr[node + 1];
    int e = e0;
    for (; e + 4 <= e1; e += 4) {
        int s0 = csr[e], s1 = csr[e + 1], s2 = csr[e + 2], s3 = csr[e + 3];
        float x0 = act ? xs[s0 * 9 + f] : 0.f;
        float x1 = act ? xs[s1 * 9 + f] : 0.f;
        float x2 = act ? xs[s2 * 9 + f] : 0.f;
        float x3 = act ? xs[s3 * 9 + f] : 0.f;
        acc += (x0 + x1) + (x2 + x3);
    }
    for (; e < e1; ++e) {
        int sA = csr[e];
        acc += act ? xs[sA * 9 + f] : 0.f;
    }
    float v = act ? dinv[node] * acc : 0.f;
    __hip_bfloat16* op = aggx_bf + (size_t)node * 32;
    union { __hip_bfloat16 h; short s; } u;
    u.h = __float2bfloat16(v);
    reinterpret_cast<short*>(op)[f] = u.s;
    reinterpret_cast<short*>(op)[16 + f] = 0;
}

// ---------------- Fused layer1-MFMA + layer2 GEMM (r23 structure) ----------------

__global__ __launch_bounds__(512, 2) void k_l12(const __hip_bfloat16* __restrict__ aggx_bf,
                       const __hip_bfloat16* __restrict__ W1frag,
                       const __hip_bfloat16* __restrict__ W2frag,
                       const float* __restrict__ b1,
                       const float* __restrict__ dinv,
                       __hip_bfloat16* __restrict__ t2, int n, int npair) {
    __shared__ short h1s[8][2][16][40];   // 20 KB: per-wave 2 tiles x 16 rows x 32 cols
    int t = threadIdx.x;
    int wid = t >> 6, lane = t & 63;
    int pair = blockIdx.x * 8 + wid;
    if (pair >= npair) return;
    int r = lane & 15, quad = lane >> 4;
    short (*hs0)[40] = h1s[wid][0];
    short (*hs1)[40] = h1s[wid][1];

    int m0 = pair << 5;
    short8 aagg0 = *reinterpret_cast<const short8*>(
        aggx_bf + (size_t)(m0 + r) * 32 + quad * 8);
    short8 aagg1 = *reinterpret_cast<const short8*>(
        aggx_bf + (size_t)(m0 + 16 + r) * 32 + quad * 8);

    float4v acc0[8], acc1[8];
#pragma unroll
    for (int cg = 0; cg < 8; ++cg) {
        acc0[cg] = (float4v){0, 0, 0, 0};
        acc1[cg] = (float4v){0, 0, 0, 0};
    }

    for (int kt = 0; kt < 16; ++kt) {
        short8 bf0 = *reinterpret_cast<const short8*>(
            W1frag + ((size_t)(2 * kt) * 64 + lane) * 8);
        short8 bf1 = *reinterpret_cast<const short8*>(
            W1frag + ((size_t)(2 * kt + 1) * 64 + lane) * 8);
        float4v c00 = __builtin_amdgcn_mfma_f32_16x16x32_bf16(
            aagg0, bf0, (float4v){0, 0, 0, 0}, 0, 0, 0);
        float4v c01 = __builtin_amdgcn_mfma_f32_16x16x32_bf16(
            aagg0, bf1, (float4v){0, 0, 0, 0}, 0, 0, 0);
        float4v c10 = __builtin_amdgcn_mfma_f32_16x16x32_bf16(
            aagg1, bf0, (float4v){0, 0, 0, 0}, 0, 0, 0);
        float4v c11 = __builtin_amdgcn_mfma_f32_16x16x32_bf16(
            aagg1, bf1, (float4v){0, 0, 0, 0}, 0, 0, 0);
        float bb0 = b1[kt * 32 + r];
        float bb1 = b1[kt * 32 + 16 + r];
        short8 bfr[8];
#pragma unroll
        for (int cg = 0; cg < 8; ++cg)
            bfr[cg] = *reinterpret_cast<const short8*>(
                W2frag + (size_t)(((kt * 4 + quad) * 128) + cg * 16 + r) * 8);
#pragma unroll
        for (int i = 0; i < 4; ++i) {
            int row = quad * 4 + i;
            hs0[row][r]      = f2bf_bits(fmaxf(c00[i] + bb0, 0.f));
            hs0[row][16 + r] = f2bf_bits(fmaxf(c01[i] + bb1, 0.f));
            hs1[row][r]      = f2bf_bits(fmaxf(c10[i] + bb0, 0.f));
            hs1[row][16 + r] = f2bf_bits(fmaxf(c11[i] + bb1, 0.f));
        }
        short8 am0 = *reinterpret_cast<const short8*>(&hs0[r][quad * 8]);
        short8 am1 = *reinterpret_cast<const short8*>(&hs1[r][quad * 8]);
#pragma unroll
        for (int cg = 0; cg < 8; ++cg) {
            acc0[cg] = __builtin_amdgcn_mfma_f32_16x16x32_bf16(am0, bfr[cg], acc0[cg], 0, 0, 0);
            acc1[cg] = __builtin_amdgcn_mfma_f32_16x16x32_bf16(am1, bfr[cg], acc1[cg], 0, 0, 0);
        }
    }

#pragma unroll
    for (int i = 0; i < 4; ++i) {
        int node0 = m0 + quad * 4 + i;
        if (node0 < n) {
            float di = dinv[node0];
            __hip_bfloat16* op = t2 + (size_t)node0 * 128 + r;
#pragma unroll
            for (int cg = 0; cg < 8; ++cg)
                op[cg * 16] = __float2bfloat16(di * acc0[cg][i]);
        }
        int node1 = m0 + 16 + quad * 4 + i;
        if (node1 < n) {
            float di = dinv[node1];
            __hip_bfloat16* op = t2 + (size_t)node1 * 128 + r;
#pragma unroll
            for (int cg = 0; cg < 8; ++cg)
                op[cg * 16] = __float2bfloat16(di * acc1[cg][i]);
        }
    }
}

// ---------------- Layer 2 aggregate + layer-3 matmul, XCD-sliced ----------------
// r26: block bid processes channel slice (bid&7) of node chunk (bid>>3).
// Round-robin dispatch maps bid%8 -> XCD, so each XCD touches only 32B of
// each t2 row: working set 3.2 MB < 4 MiB per-XCD L2 -> gathers become L2
// hits after warmup (vs 12.8 MB thrashing before).  Per-slice partial W3
// dot-products are combined via 2 atomicAdds per (node,slice) into zeroed t3.
// 256 thr = 32 nodes x 8 lanes; each lane owns one uint (2 channels).

__global__ __launch_bounds__(256) void k_agg2s(const uint* __restrict__ t2u,
                       const float* __restrict__ dinv,
                       const int* __restrict__ row_ptr, const int* __restrict__ csr,
                       const float* __restrict__ b2, const float* __restrict__ W3,
                       float2* __restrict__ t3, int n) {
    int slice = blockIdx.x & 7;
    int chunk = blockIdx.x >> 3;
    int t = threadIdx.x;
    int node = chunk * 32 + (t >> 3);
    if (node >= n) return;
    int sub = t & 7;
    int off = slice * 8 + sub;           // uint index within 64-uint row

    float2 p0 = up_bf2(t2u[(size_t)node * 64 + off]);  // self (t2' = dinv*t2)
    float a0 = p0.x, a1 = p0.y;

    int e0 = row_ptr[node], e1 = row_ptr[node + 1];
    int e = e0;
    for (; e + 8 <= e1; e += 8) {
        int si[8];
        uint ri[8];
#pragma unroll
        for (int j = 0; j < 8; ++j) si[j] = csr[e + j];
#pragma unroll
        for (int j = 0; j < 8; ++j) ri[j] = t2u[(size_t)si[j] * 64 + off];
#pragma unroll
        for (int j = 0; j < 8; ++j) {
            float2 q = up_bf2(ri[j]);
            a0 += q.x;
            a1 += q.y;
        }
    }
    for (; e < e1; ++e) {
        float2 q = up_bf2(t2u[(size_t)csr[e] * 64 + off]);
        a0 += q.x;
        a1 += q.y;
    }

    float di = dinv[node];
    int c = off * 2;                     // global channel
    float2 bb = *reinterpret_cast<const float2*>(b2 + c);
    float h0 = fmaxf(di * a0 + bb.x, 0.f);
    float h1 = fmaxf(di * a1 + bb.y, 0.f);
    float4 wv = *reinterpret_cast<const float4*>(W3 + 2 * c);  // rows c, c+1
    float c0 = h0 * wv.x + h1 * wv.z;
    float c1 = h0 * wv.y + h1 * wv.w;
    // reduce over the 8 sub-lanes of this node (contiguous lanes, in-wave)
    c0 += __shfl_xor(c0, 1); c1 += __shfl_xor(c1, 1);
    c0 += __shfl_xor(c0, 2); c1 += __shfl_xor(c1, 2);
    c0 += __shfl_xor(c0, 4); c1 += __shfl_xor(c1, 4);
    if (sub == 0) {
        atomicAdd(&t3[node].x, di * c0);  // prescaled partial
        atomicAdd(&t3[node].y, di * c1);
    }
}

// ---------------- Layer 3 aggregate + log_softmax ----------------

__global__ void k_agg3(const float2* __restrict__ t3, const float* __restrict__ dinv,
                       const int* __restrict__ row_ptr, const int* __restrict__ csr,
                       const float* __restrict__ b3, float2* __restrict__ outv, int n) {
    int node = blockIdx.x * blockDim.x + threadIdx.x;
    if (node >= n) return;
    float2 s = t3[node];  // self (t3' = dinv*t3)
    float a0 = s.x, a1 = s.y;
    int e0 = row_ptr[node], e1 = row_ptr[node + 1];
    int e = e0;
    for (; e + 4 <= e1; e += 4) {
        int s0 = csr[e], s1 = csr[e + 1], s2 = csr[e + 2], s3 = csr[e + 3];
        float2 q0 = t3[s0], q1 = t3[s1], q2 = t3[s2], q3 = t3[s3];
        a0 += q0.x + q1.x + q2.x + q3.x;
        a1 += q0.y + q1.y + q2.y + q3.y;
    }
    for (; e < e1; ++e) {
        float2 q0 = t3[csr[e]];
        a0 += q0.x;
        a1 += q0.y;
    }
    float di = dinv[node];
    float z0 = di * a0 + b3[0];
    float z1 = di * a1 + b3[1];
    float m = fmaxf(z0, z1);
    float lse = m + logf(expf(z0 - m) + expf(z1 - m));
    outv[node] = make_float2(z0 - lse, z1 - lse);
}

// ---------------- launch ----------------

extern "C" void kernel_launch(void* const* d_in, const int* in_sizes, int n_in,
                              void* d_out, int out_size, void* d_ws, size_t ws_size,
                              hipStream_t stream) {
    const float* x  = (const float*)d_in[0];
    const float* W1 = (const float*)d_in[1];
    const float* b1 = (const float*)d_in[2];
    const float* W2 = (const float*)d_in[3];
    const float* b2 = (const float*)d_in[4];
    const float* W3 = (const float*)d_in[5];
    const float* b3 = (const float*)d_in[6];
    const int* edges = (const int*)d_in[7];

    int n = in_sizes[0] / 9;
    int E = in_sizes[7] / 2;
    const int* src = edges;
    const int* dst = edges + E;

    char* p = (char*)d_ws;
    auto alloc = [&](size_t bytes) {
        char* q = p;
        p += (bytes + 511) & ~(size_t)511;
        return q;
    };
    float* dinv       = (float*)alloc((size_t)n * 4);
    int*   row_ptr    = (int*)alloc((size_t)(n + 1) * 4);
    int*   csr        = (int*)alloc((size_t)E * 4);
    int*   histBlk    = (int*)alloc((size_t)256 * NBLK * 4);
    int*   baseBlk    = (int*)alloc((size_t)256 * NBLK * 4);
    int*   btot       = (int*)alloc(256 * 4);
    int*   bucketBase = (int*)alloc(256 * 4);
    uint*  binned     = (uint*)alloc((size_t)E * 4);
    float* xs         = (float*)alloc((size_t)n * 9 * 4);
    __hip_bfloat16* aggx_bf = (__hip_bfloat16*)alloc((size_t)(n + 64) * 32 * 2);
    __hip_bfloat16* W1frag  = (__hip_bfloat16*)alloc((size_t)32 * 64 * 8 * 2);
    __hip_bfloat16* W2frag  = (__hip_bfloat16*)alloc((size_t)64 * 128 * 8 * 2);
    __hip_bfloat16* t2 = (__hip_bfloat16*)alloc((size_t)n * 128 * 2);
    float2* t3 = (float2*)alloc((size_t)n * 8);

    const int B = 256;
    int shift = 8;  // packed binned requires shift==8 (dst_local 8b) and n < 2^24
    int nbuck = ((n - 1) >> shift) + 1;
    int chunk = (E + NBLK - 1) / NBLK;

    hipMemsetAsync(t3, 0, (size_t)n * 8, stream);  // atomic partial-sum target

    k_hist<<<NBLK, B, 0, stream>>>(dst, E, chunk, shift, nbuck, histBlk);
    k_btot<<<nbuck, B, 0, stream>>>(histBlk, btot);
    k_bscan<<<nbuck, B, 0, stream>>>(histBlk, btot, nbuck, baseBlk, bucketBase);
    k_scatterbin<<<NBLK, B, 0, stream>>>(src, dst, E, chunk, shift, nbuck, baseBlk, binned);
    k_csrbuild<<<nbuck, B, 0, stream>>>(binned, bucketBase, x, E, shift, n, nbuck,
                                        row_ptr, dinv, xs, csr);

    int nagg = (n + 15) / 16;                 // 3125 agg1 blocks (+8 W1frag, +32 W2frag)
    k_agg1w<<<nagg + 40, B, 0, stream>>>(xs, dinv, row_ptr, csr, W1, W2,
                                         aggx_bf, W1frag, W2frag, n, nagg);

    int ntile = (n + 15) / 16;                // 3125
    int npair = (ntile + 1) / 2;              // 1563 wave-tasks (32 rows each)
    k_l12<<<(npair + 7) / 8, 512, 0, stream>>>(aggx_bf, W1frag, W2frag, b1, dinv, t2, n, npair);

    int nchunk = (n + 31) / 32;               // 1563 node chunks x 8 slices
    k_agg2s<<<nchunk * 8, B, 0, stream>>>((const uint*)t2, dinv, row_ptr, csr, b2, W3, t3, n);

    k_agg3<<<(n + B - 1) / B, B, 0, stream>>>(t3, dinv, row_ptr, csr, b3, (float2*)d_out, n);
}

// Round 8
// 207.755 us; speedup vs baseline: 1.1716x; 1.1251x over previous
//
#include <hip/hip_runtime.h>
#include <hip/hip_bf16.h>

typedef __attribute__((ext_vector_type(8))) short short8;
typedef __attribute__((ext_vector_type(4))) float float4v;
typedef unsigned int uint;

#define NBLK 192  // blocks for hist/scatterbin passes

static __device__ __forceinline__ float2 up_bf2(uint v) {
    float2 r;
    r.x = __uint_as_float(v << 16);
    r.y = __uint_as_float(v & 0xffff0000u);
    return r;
}
static __device__ __forceinline__ short f2bf_bits(float x) {
    union { __hip_bfloat16 h; short s; } u;
    u.h = __float2bfloat16(x);
    return u.s;
}

// ---------------- per-(bucket,block) histogram, LDS only ----------------

__global__ __launch_bounds__(256) void k_hist(const int* __restrict__ dst, int E, int chunk,
        int shift, int nbuck, int* __restrict__ histBlk) {
    __shared__ int h[256];
    h[threadIdx.x] = 0;
    __syncthreads();
    int blk = blockIdx.x;
    int e0 = blk * chunk, e1 = min(E, e0 + chunk);
    for (int e = e0 + threadIdx.x; e < e1; e += 256)
        atomicAdd(&h[dst[e] >> shift], 1);
    __syncthreads();
    if (threadIdx.x < nbuck) histBlk[threadIdx.x * NBLK + blk] = h[threadIdx.x];
}

// ---------------- bucket totals ----------------

__global__ __launch_bounds__(256) void k_btot(const int* __restrict__ histBlk,
                                              int* __restrict__ btot) {
    __shared__ int s[256];
    int b = blockIdx.x, t = threadIdx.x;
    s[t] = (t < NBLK) ? histBlk[b * NBLK + t] : 0;
    __syncthreads();
    for (int off = 128; off; off >>= 1) {
        if (t < off) s[t] += s[t + off];
        __syncthreads();
    }
    if (t == 0) btot[b] = s[0];
}

// ---------------- per-(bucket,block) bases + bucket bases ----------------

__global__ __launch_bounds__(256) void k_bscan(const int* __restrict__ histBlk,
        const int* __restrict__ btot, int nbuck,
        int* __restrict__ baseBlk, int* __restrict__ bucketBase) {
    __shared__ int s[256], sb[256];
    int b = blockIdx.x, t = threadIdx.x;
    int v = (t < NBLK) ? histBlk[b * NBLK + t] : 0;
    s[t] = v;
    sb[t] = (t < nbuck) ? btot[t] : 0;
    __syncthreads();
    for (int off = 1; off < 256; off <<= 1) {
        int u = (t >= off) ? s[t - off] : 0;
        int u2 = (t >= off) ? sb[t - off] : 0;
        __syncthreads();
        s[t] += u;
        sb[t] += u2;
        __syncthreads();
    }
    int base = (b > 0) ? sb[b - 1] : 0;  // exclusive prefix of bucket totals
    if (t < NBLK) baseBlk[b * NBLK + t] = base + s[t] - v;
    if (t == 0) bucketBase[b] = base;
}

// ---------------- scatter into per-(bucket,block) slices, packed payload ----------------
// binned word = src (24b) | dst_local (8b).  Requires n < 2^24 and shift == 8.

__global__ __launch_bounds__(256) void k_scatterbin(const int* __restrict__ src,
        const int* __restrict__ dst, int E, int chunk, int shift, int nbuck,
        const int* __restrict__ baseBlk, uint* __restrict__ binned) {
    __shared__ int cur[256];
    int blk = blockIdx.x;
    if (threadIdx.x < nbuck) cur[threadIdx.x] = baseBlk[threadIdx.x * NBLK + blk];
    __syncthreads();
    int e0 = blk * chunk, e1 = min(E, e0 + chunk);
    int mask = (1 << shift) - 1;
    for (int e = e0 + threadIdx.x; e < e1; e += 256) {
        int d = dst[e];
        int pos = atomicAdd(&cur[d >> shift], 1);
        binned[pos] = (uint)src[e] | ((uint)(d & mask) << 24);
    }
}

// ---------------- per-bucket: counts -> row_ptr/dinv/xs, then exact csr scatter ----------------

__global__ __launch_bounds__(256) void k_csrbuild(const uint* __restrict__ binned,
        const int* __restrict__ bucketBase, const float* __restrict__ x,
        int E, int shift, int n, int nbuck,
        int* __restrict__ row_ptr, float* __restrict__ dinv, float* __restrict__ xs,
        int* __restrict__ csr) {
    __shared__ int cnt[256], lcur[256];
    int b = blockIdx.x, t = threadIdx.x;
    cnt[t] = 0;
    __syncthreads();
    int lo = bucketBase[b];
    int hi = (b + 1 < nbuck) ? bucketBase[b + 1] : E;
    for (int e = lo + t; e < hi; e += 256)
        atomicAdd(&cnt[binned[e] >> 24], 1);
    __syncthreads();
    int c = cnt[t];
    lcur[t] = c;
    __syncthreads();
    for (int off = 1; off < 256; off <<= 1) {
        int u = (t >= off) ? lcur[t - off] : 0;
        __syncthreads();
        lcur[t] += u;
        __syncthreads();
    }
    int node0 = b << shift;
    int nodeEnd = min(n, (b + 1) << shift);
    int cntNodes = nodeEnd - node0;
    int myBase = lo + lcur[t] - c;  // exclusive prefix within bucket
    if (t < cntNodes) {
        row_ptr[node0 + t] = myBase;
        dinv[node0 + t] = rsqrtf((float)(c + 1));  // +1 self-loop
    }
    if (b == nbuck - 1 && t == 0) row_ptr[n] = E;
    for (int j = t; j < cntNodes * 9; j += 256) {
        int nl = j / 9, f = j - nl * 9;
        float dnl = rsqrtf((float)(cnt[nl] + 1));
        xs[(size_t)(node0 + nl) * 9 + f] = dnl * x[(size_t)(node0 + nl) * 9 + f];
    }
    __syncthreads();
    lcur[t] = myBase;  // running cursors
    __syncthreads();
    for (int e = lo + t; e < hi; e += 256) {
        uint p = binned[e];
        int pos = atomicAdd(&lcur[p >> 24], 1);
        csr[pos] = (int)(p & 0xFFFFFF);
    }
}

// ---------------- Layer 1 aggregate (+ fused W1/W2 frag prebuild) ----------------

__global__ __launch_bounds__(256) void k_agg1w(const float* __restrict__ xs,
                       const float* __restrict__ dinv,
                       const int* __restrict__ row_ptr, const int* __restrict__ csr,
                       const float* __restrict__ W1, const float* __restrict__ W2,
                       __hip_bfloat16* __restrict__ aggx_bf,
                       __hip_bfloat16* __restrict__ W1frag,
                       __hip_bfloat16* __restrict__ W2frag, int n, int nagg) {
    int bid = blockIdx.x;
    if (bid >= nagg) {
        int xb = bid - nagg;
        if (xb < 8) {  // W1frag role (8 blocks, 2048 threads)
            int t = xb * 256 + threadIdx.x;
            if (t < 32 * 64) {
                int ctile = t >> 6, lane = t & 63;
                int col = ctile * 16 + (lane & 15);
                int k0 = (lane >> 4) * 8;
                short8 o;
#pragma unroll
                for (int j = 0; j < 8; ++j) {
                    int k = k0 + j;
                    o[j] = f2bf_bits(k < 9 ? W1[k * 512 + col] : 0.f);
                }
                *reinterpret_cast<short8*>(W1frag + (size_t)t * 8) = o;
            }
        } else {  // W2frag role (32 blocks): W2frag[(kb*128+c)*8+j] = bf16(W2[(kb*8+j)*128+c])
            int t = (xb - 8) * 256 + threadIdx.x;
            if (t < 64 * 128) {
                int kb = t >> 7, c = t & 127;
                const float* wp = W2 + (size_t)(kb * 8) * 128 + c;
                short8 o;
#pragma unroll
                for (int j = 0; j < 8; ++j) o[j] = f2bf_bits(wp[j * 128]);
                *reinterpret_cast<short8*>(W2frag + (size_t)t * 8) = o;
            }
        }
        return;
    }
    int node = bid * 16 + (threadIdx.x >> 4);
    if (node >= n) return;
    int f = threadIdx.x & 15;
    bool act = f < 9;
    float acc = act ? xs[node * 9 + f] : 0.f;  // self-loop (xs = dinv*x)
    int e0 = row_ptr[node], e1 = row_ptr[node + 1];
    int e = e0;
    for (; e + 4 <= e1; e += 4) {
        int s0 = csr[e], s1 = csr[e + 1], s2 = csr[e + 2], s3 = csr[e + 3];
        float x0 = act ? xs[s0 * 9 + f] : 0.f;
        float x1 = act ? xs[s1 * 9 + f] : 0.f;
        float x2 = act ? xs[s2 * 9 + f] : 0.f;
        float x3 = act ? xs[s3 * 9 + f] : 0.f;
        acc += (x0 + x1) + (x2 + x3);
    }
    for (; e < e1; ++e) {
        int sA = csr[e];
        acc += act ? xs[sA * 9 + f] : 0.f;
    }
    float v = act ? dinv[node] * acc : 0.f;
    __hip_bfloat16* op = aggx_bf + (size_t)node * 32;
    union { __hip_bfloat16 h; short s; } u;
    u.h = __float2bfloat16(v);
    reinterpret_cast<short*>(op)[f] = u.s;
    reinterpret_cast<short*>(op)[16 + f] = 0;
}

// ---------------- Fused layer1-MFMA + layer2 GEMM (r23 structure) ----------------

__global__ __launch_bounds__(512, 2) void k_l12(const __hip_bfloat16* __restrict__ aggx_bf,
                       const __hip_bfloat16* __restrict__ W1frag,
                       const __hip_bfloat16* __restrict__ W2frag,
                       const float* __restrict__ b1,
                       const float* __restrict__ dinv,
                       __hip_bfloat16* __restrict__ t2, int n, int npair) {
    __shared__ short h1s[8][2][16][40];   // 20 KB: per-wave 2 tiles x 16 rows x 32 cols
    int t = threadIdx.x;
    int wid = t >> 6, lane = t & 63;
    int pair = blockIdx.x * 8 + wid;
    if (pair >= npair) return;
    int r = lane & 15, quad = lane >> 4;
    short (*hs0)[40] = h1s[wid][0];
    short (*hs1)[40] = h1s[wid][1];

    int m0 = pair << 5;
    short8 aagg0 = *reinterpret_cast<const short8*>(
        aggx_bf + (size_t)(m0 + r) * 32 + quad * 8);
    short8 aagg1 = *reinterpret_cast<const short8*>(
        aggx_bf + (size_t)(m0 + 16 + r) * 32 + quad * 8);

    float4v acc0[8], acc1[8];
#pragma unroll
    for (int cg = 0; cg < 8; ++cg) {
        acc0[cg] = (float4v){0, 0, 0, 0};
        acc1[cg] = (float4v){0, 0, 0, 0};
    }

    for (int kt = 0; kt < 16; ++kt) {
        short8 bf0 = *reinterpret_cast<const short8*>(
            W1frag + ((size_t)(2 * kt) * 64 + lane) * 8);
        short8 bf1 = *reinterpret_cast<const short8*>(
            W1frag + ((size_t)(2 * kt + 1) * 64 + lane) * 8);
        float4v c00 = __builtin_amdgcn_mfma_f32_16x16x32_bf16(
            aagg0, bf0, (float4v){0, 0, 0, 0}, 0, 0, 0);
        float4v c01 = __builtin_amdgcn_mfma_f32_16x16x32_bf16(
            aagg0, bf1, (float4v){0, 0, 0, 0}, 0, 0, 0);
        float4v c10 = __builtin_amdgcn_mfma_f32_16x16x32_bf16(
            aagg1, bf0, (float4v){0, 0, 0, 0}, 0, 0, 0);
        float4v c11 = __builtin_amdgcn_mfma_f32_16x16x32_bf16(
            aagg1, bf1, (float4v){0, 0, 0, 0}, 0, 0, 0);
        float bb0 = b1[kt * 32 + r];
        float bb1 = b1[kt * 32 + 16 + r];
        short8 bfr[8];
#pragma unroll
        for (int cg = 0; cg < 8; ++cg)
            bfr[cg] = *reinterpret_cast<const short8*>(
                W2frag + (size_t)(((kt * 4 + quad) * 128) + cg * 16 + r) * 8);
#pragma unroll
        for (int i = 0; i < 4; ++i) {
            int row = quad * 4 + i;
            hs0[row][r]      = f2bf_bits(fmaxf(c00[i] + bb0, 0.f));
            hs0[row][16 + r] = f2bf_bits(fmaxf(c01[i] + bb1, 0.f));
            hs1[row][r]      = f2bf_bits(fmaxf(c10[i] + bb0, 0.f));
            hs1[row][16 + r] = f2bf_bits(fmaxf(c11[i] + bb1, 0.f));
        }
        short8 am0 = *reinterpret_cast<const short8*>(&hs0[r][quad * 8]);
        short8 am1 = *reinterpret_cast<const short8*>(&hs1[r][quad * 8]);
#pragma unroll
        for (int cg = 0; cg < 8; ++cg) {
            acc0[cg] = __builtin_amdgcn_mfma_f32_16x16x32_bf16(am0, bfr[cg], acc0[cg], 0, 0, 0);
            acc1[cg] = __builtin_amdgcn_mfma_f32_16x16x32_bf16(am1, bfr[cg], acc1[cg], 0, 0, 0);
        }
    }

#pragma unroll
    for (int i = 0; i < 4; ++i) {
        int node0 = m0 + quad * 4 + i;
        if (node0 < n) {
            float di = dinv[node0];
            __hip_bfloat16* op = t2 + (size_t)node0 * 128 + r;
#pragma unroll
            for (int cg = 0; cg < 8; ++cg)
                op[cg * 16] = __float2bfloat16(di * acc0[cg][i]);
        }
        int node1 = m0 + 16 + quad * 4 + i;
        if (node1 < n) {
            float di = dinv[node1];
            __hip_bfloat16* op = t2 + (size_t)node1 * 128 + r;
#pragma unroll
            for (int cg = 0; cg < 8; ++cg)
                op[cg * 16] = __float2bfloat16(di * acc1[cg][i]);
        }
    }
}

// ---------------- Layer 2 aggregate + layer-3 matmul, XCD-sliced v2 ----------------
// r27: slice = 64 B (32 channels) = one full cache line; 4 slices, slice = bid&3
// so XCDs i and i+4 share slice i -> per-XCD t2 working set = n*64B = 3.2 MB
// < 4 MiB L2.  uint2 (8 B/lane) loads, 8 lanes/node/slice, 16-deep edge unroll
// -> 8 KB in flight per wave (2x r20) against L2-hit latency.  Partial W3
// dot-products combined via 2 atomicAdds per (node,slice) into zeroed t3.

__global__ __launch_bounds__(256) void k_agg2s(const uint2* __restrict__ t2v,
                       const float* __restrict__ dinv,
                       const int* __restrict__ row_ptr, const int* __restrict__ csr,
                       const float* __restrict__ b2, const float* __restrict__ W3,
                       float2* __restrict__ t3, int n) {
    int slice = blockIdx.x & 3;
    int chunk = blockIdx.x >> 2;
    int t = threadIdx.x;
    int node = chunk * 32 + (t >> 3);
    if (node >= n) return;
    int sub = t & 7;
    int off = slice * 8 + sub;           // uint2 index within 32-uint2 row

    uint2 sv = t2v[(size_t)node * 32 + off];  // self (t2' = dinv*t2)
    float2 pa = up_bf2(sv.x), pb = up_bf2(sv.y);
    float a0 = pa.x, a1 = pa.y, a2 = pb.x, a3 = pb.y;

    int e0 = row_ptr[node], e1 = row_ptr[node + 1];
    int e = e0;
    for (; e + 16 <= e1; e += 16) {      // 16 gathers in flight per lane
        int si[16];
        uint2 ri[16];
#pragma unroll
        for (int j = 0; j < 16; ++j) si[j] = csr[e + j];
#pragma unroll
        for (int j = 0; j < 16; ++j) ri[j] = t2v[(size_t)si[j] * 32 + off];
#pragma unroll
        for (int j = 0; j < 16; ++j) {
            float2 qa = up_bf2(ri[j].x), qb = up_bf2(ri[j].y);
            a0 += qa.x; a1 += qa.y; a2 += qb.x; a3 += qb.y;
        }
    }
    for (; e + 4 <= e1; e += 4) {
        int s0 = csr[e], s1 = csr[e + 1], s2 = csr[e + 2], s3 = csr[e + 3];
        uint2 r0 = t2v[(size_t)s0 * 32 + off];
        uint2 r1 = t2v[(size_t)s1 * 32 + off];
        uint2 r2 = t2v[(size_t)s2 * 32 + off];
        uint2 r3 = t2v[(size_t)s3 * 32 + off];
        float2 qa = up_bf2(r0.x), qb = up_bf2(r0.y);
        float2 qc = up_bf2(r1.x), qd = up_bf2(r1.y);
        float2 qe = up_bf2(r2.x), qf = up_bf2(r2.y);
        float2 qg = up_bf2(r3.x), qh = up_bf2(r3.y);
        a0 += (qa.x + qc.x) + (qe.x + qg.x);
        a1 += (qa.y + qc.y) + (qe.y + qg.y);
        a2 += (qb.x + qd.x) + (qf.x + qh.x);
        a3 += (qb.y + qd.y) + (qf.y + qh.y);
    }
    for (; e < e1; ++e) {
        uint2 rv = t2v[(size_t)csr[e] * 32 + off];
        float2 qa = up_bf2(rv.x), qb = up_bf2(rv.y);
        a0 += qa.x; a1 += qa.y; a2 += qb.x; a3 += qb.y;
    }

    float di = dinv[node];
    int c = off * 4;                     // global channel (4 channels per lane)
    float4 bb = *reinterpret_cast<const float4*>(b2 + c);
    float h0 = fmaxf(di * a0 + bb.x, 0.f);
    float h1 = fmaxf(di * a1 + bb.y, 0.f);
    float h2 = fmaxf(di * a2 + bb.z, 0.f);
    float h3 = fmaxf(di * a3 + bb.w, 0.f);
    float4 wlo = *reinterpret_cast<const float4*>(W3 + 2 * c);      // rows c, c+1
    float4 whi = *reinterpret_cast<const float4*>(W3 + 2 * c + 4);  // rows c+2, c+3
    float c0 = h0 * wlo.x + h1 * wlo.z + h2 * whi.x + h3 * whi.z;
    float c1 = h0 * wlo.y + h1 * wlo.w + h2 * whi.y + h3 * whi.w;
    // reduce over the 8 sub-lanes of this node (contiguous lanes, in-wave)
    c0 += __shfl_xor(c0, 1); c1 += __shfl_xor(c1, 1);
    c0 += __shfl_xor(c0, 2); c1 += __shfl_xor(c1, 2);
    c0 += __shfl_xor(c0, 4); c1 += __shfl_xor(c1, 4);
    if (sub == 0) {
        atomicAdd(&t3[node].x, di * c0);  // prescaled partial
        atomicAdd(&t3[node].y, di * c1);
    }
}

// ---------------- Layer 3 aggregate + log_softmax ----------------

__global__ void k_agg3(const float2* __restrict__ t3, const float* __restrict__ dinv,
                       const int* __restrict__ row_ptr, const int* __restrict__ csr,
                       const float* __restrict__ b3, float2* __restrict__ outv, int n) {
    int node = blockIdx.x * blockDim.x + threadIdx.x;
    if (node >= n) return;
    float2 s = t3[node];  // self (t3' = dinv*t3)
    float a0 = s.x, a1 = s.y;
    int e0 = row_ptr[node], e1 = row_ptr[node + 1];
    int e = e0;
    for (; e + 4 <= e1; e += 4) {
        int s0 = csr[e], s1 = csr[e + 1], s2 = csr[e + 2], s3 = csr[e + 3];
        float2 q0 = t3[s0], q1 = t3[s1], q2 = t3[s2], q3 = t3[s3];
        a0 += q0.x + q1.x + q2.x + q3.x;
        a1 += q0.y + q1.y + q2.y + q3.y;
    }
    for (; e < e1; ++e) {
        float2 q0 = t3[csr[e]];
        a0 += q0.x;
        a1 += q0.y;
    }
    float di = dinv[node];
    float z0 = di * a0 + b3[0];
    float z1 = di * a1 + b3[1];
    float m = fmaxf(z0, z1);
    float lse = m + logf(expf(z0 - m) + expf(z1 - m));
    outv[node] = make_float2(z0 - lse, z1 - lse);
}

// ---------------- launch ----------------

extern "C" void kernel_launch(void* const* d_in, const int* in_sizes, int n_in,
                              void* d_out, int out_size, void* d_ws, size_t ws_size,
                              hipStream_t stream) {
    const float* x  = (const float*)d_in[0];
    const float* W1 = (const float*)d_in[1];
    const float* b1 = (const float*)d_in[2];
    const float* W2 = (const float*)d_in[3];
    const float* b2 = (const float*)d_in[4];
    const float* W3 = (const float*)d_in[5];
    const float* b3 = (const float*)d_in[6];
    const int* edges = (const int*)d_in[7];

    int n = in_sizes[0] / 9;
    int E = in_sizes[7] / 2;
    const int* src = edges;
    const int* dst = edges + E;

    char* p = (char*)d_ws;
    auto alloc = [&](size_t bytes) {
        char* q = p;
        p += (bytes + 511) & ~(size_t)511;
        return q;
    };
    float* dinv       = (float*)alloc((size_t)n * 4);
    int*   row_ptr    = (int*)alloc((size_t)(n + 1) * 4);
    int*   csr        = (int*)alloc((size_t)E * 4);
    int*   histBlk    = (int*)alloc((size_t)256 * NBLK * 4);
    int*   baseBlk    = (int*)alloc((size_t)256 * NBLK * 4);
    int*   btot       = (int*)alloc(256 * 4);
    int*   bucketBase = (int*)alloc(256 * 4);
    uint*  binned     = (uint*)alloc((size_t)E * 4);
    float* xs         = (float*)alloc((size_t)n * 9 * 4);
    __hip_bfloat16* aggx_bf = (__hip_bfloat16*)alloc((size_t)(n + 64) * 32 * 2);
    __hip_bfloat16* W1frag  = (__hip_bfloat16*)alloc((size_t)32 * 64 * 8 * 2);
    __hip_bfloat16* W2frag  = (__hip_bfloat16*)alloc((size_t)64 * 128 * 8 * 2);
    __hip_bfloat16* t2 = (__hip_bfloat16*)alloc((size_t)n * 128 * 2);
    float2* t3 = (float2*)alloc((size_t)n * 8);

    const int B = 256;
    int shift = 8;  // packed binned requires shift==8 (dst_local 8b) and n < 2^24
    int nbuck = ((n - 1) >> shift) + 1;
    int chunk = (E + NBLK - 1) / NBLK;

    hipMemsetAsync(t3, 0, (size_t)n * 8, stream);  // atomic partial-sum target

    k_hist<<<NBLK, B, 0, stream>>>(dst, E, chunk, shift, nbuck, histBlk);
    k_btot<<<nbuck, B, 0, stream>>>(histBlk, btot);
    k_bscan<<<nbuck, B, 0, stream>>>(histBlk, btot, nbuck, baseBlk, bucketBase);
    k_scatterbin<<<NBLK, B, 0, stream>>>(src, dst, E, chunk, shift, nbuck, baseBlk, binned);
    k_csrbuild<<<nbuck, B, 0, stream>>>(binned, bucketBase, x, E, shift, n, nbuck,
                                        row_ptr, dinv, xs, csr);

    int nagg = (n + 15) / 16;                 // 3125 agg1 blocks (+8 W1frag, +32 W2frag)
    k_agg1w<<<nagg + 40, B, 0, stream>>>(xs, dinv, row_ptr, csr, W1, W2,
                                         aggx_bf, W1frag, W2frag, n, nagg);

    int ntile = (n + 15) / 16;                // 3125
    int npair = (ntile + 1) / 2;              // 1563 wave-tasks (32 rows each)
    k_l12<<<(npair + 7) / 8, 512, 0, stream>>>(aggx_bf, W1frag, W2frag, b1, dinv, t2, n, npair);

    int nchunk = (n + 31) / 32;               // 1563 node chunks x 4 slices
    k_agg2s<<<nchunk * 4, B, 0, stream>>>((const uint2*)t2, dinv, row_ptr, csr, b2, W3, t3, n);

    k_agg3<<<(n + B - 1) / B, B, 0, stream>>>(t3, dinv, row_ptr, csr, b3, (float2*)d_out, n);
}

// Round 9
// 193.475 us; speedup vs baseline: 1.2580x; 1.0738x over previous
//
#include <hip/hip_runtime.h>
#include <hip/hip_bf16.h>

typedef __attribute__((ext_vector_type(8))) short short8;
typedef __attribute__((ext_vector_type(4))) float float4v;
typedef unsigned int uint;

#define NBLK 192  // blocks for hist/scatterbin passes

static __device__ __forceinline__ float2 up_bf2(uint v) {
    float2 r;
    r.x = __uint_as_float(v << 16);
    r.y = __uint_as_float(v & 0xffff0000u);
    return r;
}
static __device__ __forceinline__ short f2bf_bits(float x) {
    union { __hip_bfloat16 h; short s; } u;
    u.h = __float2bfloat16(x);
    return u.s;
}

// ---------------- per-(bucket,block) histogram, LDS only ----------------

__global__ __launch_bounds__(256) void k_hist(const int* __restrict__ dst, int E, int chunk,
        int shift, int nbuck, int* __restrict__ histBlk) {
    __shared__ int h[256];
    h[threadIdx.x] = 0;
    __syncthreads();
    int blk = blockIdx.x;
    int e0 = blk * chunk, e1 = min(E, e0 + chunk);
    for (int e = e0 + threadIdx.x; e < e1; e += 256)
        atomicAdd(&h[dst[e] >> shift], 1);
    __syncthreads();
    if (threadIdx.x < nbuck) histBlk[threadIdx.x * NBLK + blk] = h[threadIdx.x];
}

// ---------------- bucket totals ----------------

__global__ __launch_bounds__(256) void k_btot(const int* __restrict__ histBlk,
                                              int* __restrict__ btot) {
    __shared__ int s[256];
    int b = blockIdx.x, t = threadIdx.x;
    s[t] = (t < NBLK) ? histBlk[b * NBLK + t] : 0;
    __syncthreads();
    for (int off = 128; off; off >>= 1) {
        if (t < off) s[t] += s[t + off];
        __syncthreads();
    }
    if (t == 0) btot[b] = s[0];
}

// ---------------- per-(bucket,block) bases + bucket bases ----------------

__global__ __launch_bounds__(256) void k_bscan(const int* __restrict__ histBlk,
        const int* __restrict__ btot, int nbuck,
        int* __restrict__ baseBlk, int* __restrict__ bucketBase) {
    __shared__ int s[256], sb[256];
    int b = blockIdx.x, t = threadIdx.x;
    int v = (t < NBLK) ? histBlk[b * NBLK + t] : 0;
    s[t] = v;
    sb[t] = (t < nbuck) ? btot[t] : 0;
    __syncthreads();
    for (int off = 1; off < 256; off <<= 1) {
        int u = (t >= off) ? s[t - off] : 0;
        int u2 = (t >= off) ? sb[t - off] : 0;
        __syncthreads();
        s[t] += u;
        sb[t] += u2;
        __syncthreads();
    }
    int base = (b > 0) ? sb[b - 1] : 0;  // exclusive prefix of bucket totals
    if (t < NBLK) baseBlk[b * NBLK + t] = base + s[t] - v;
    if (t == 0) bucketBase[b] = base;
}

// ---------------- scatter into per-(bucket,block) slices, packed payload ----------------
// binned word = src (24b) | dst_local (8b).  Requires n < 2^24 and shift == 8.

__global__ __launch_bounds__(256) void k_scatterbin(const int* __restrict__ src,
        const int* __restrict__ dst, int E, int chunk, int shift, int nbuck,
        const int* __restrict__ baseBlk, uint* __restrict__ binned) {
    __shared__ int cur[256];
    int blk = blockIdx.x;
    if (threadIdx.x < nbuck) cur[threadIdx.x] = baseBlk[threadIdx.x * NBLK + blk];
    __syncthreads();
    int e0 = blk * chunk, e1 = min(E, e0 + chunk);
    int mask = (1 << shift) - 1;
    for (int e = e0 + threadIdx.x; e < e1; e += 256) {
        int d = dst[e];
        int pos = atomicAdd(&cur[d >> shift], 1);
        binned[pos] = (uint)src[e] | ((uint)(d & mask) << 24);
    }
}

// ---------------- per-bucket: counts -> row_ptr/dinv/xs, then exact csr scatter ----------------

__global__ __launch_bounds__(256) void k_csrbuild(const uint* __restrict__ binned,
        const int* __restrict__ bucketBase, const float* __restrict__ x,
        int E, int shift, int n, int nbuck,
        int* __restrict__ row_ptr, float* __restrict__ dinv, float* __restrict__ xs,
        int* __restrict__ csr) {
    __shared__ int cnt[256], lcur[256];
    int b = blockIdx.x, t = threadIdx.x;
    cnt[t] = 0;
    __syncthreads();
    int lo = bucketBase[b];
    int hi = (b + 1 < nbuck) ? bucketBase[b + 1] : E;
    for (int e = lo + t; e < hi; e += 256)
        atomicAdd(&cnt[binned[e] >> 24], 1);
    __syncthreads();
    int c = cnt[t];
    lcur[t] = c;
    __syncthreads();
    for (int off = 1; off < 256; off <<= 1) {
        int u = (t >= off) ? lcur[t - off] : 0;
        __syncthreads();
        lcur[t] += u;
        __syncthreads();
    }
    int node0 = b << shift;
    int nodeEnd = min(n, (b + 1) << shift);
    int cntNodes = nodeEnd - node0;
    int myBase = lo + lcur[t] - c;  // exclusive prefix within bucket
    if (t < cntNodes) {
        row_ptr[node0 + t] = myBase;
        dinv[node0 + t] = rsqrtf((float)(c + 1));  // +1 self-loop
    }
    if (b == nbuck - 1 && t == 0) row_ptr[n] = E;
    for (int j = t; j < cntNodes * 9; j += 256) {
        int nl = j / 9, f = j - nl * 9;
        float dnl = rsqrtf((float)(cnt[nl] + 1));
        xs[(size_t)(node0 + nl) * 9 + f] = dnl * x[(size_t)(node0 + nl) * 9 + f];
    }
    __syncthreads();
    lcur[t] = myBase;  // running cursors
    __syncthreads();
    for (int e = lo + t; e < hi; e += 256) {
        uint p = binned[e];
        int pos = atomicAdd(&lcur[p >> 24], 1);
        csr[pos] = (int)(p & 0xFFFFFF);
    }
}

// ---------------- Layer 1 aggregate v2 (+ fused W1 frag prebuild) ----------------
// r28: 32 lanes/node = 2 edge-slots x 16 features, 8-deep unroll -> 16 edges
// per chunk, 8 gathers in flight per lane (4x the old MLP).  xs (1.8 MB) is
// L2-resident, so this kernel is latency x parallelism bound.  shfl_xor(16)
// merges the two edge slots.  Blocks >= nagg build W1frag.

__global__ __launch_bounds__(256) void k_agg1w(const float* __restrict__ xs,
                       const float* __restrict__ dinv,
                       const int* __restrict__ row_ptr, const int* __restrict__ csr,
                       const float* __restrict__ W1,
                       __hip_bfloat16* __restrict__ aggx_bf,
                       __hip_bfloat16* __restrict__ W1frag, int n, int nagg) {
    int bid = blockIdx.x;
    if (bid >= nagg) {  // W1frag role (8 blocks, 2048 threads)
        int t = (bid - nagg) * 256 + threadIdx.x;
        if (t < 32 * 64) {
            int ctile = t >> 6, lane = t & 63;
            int col = ctile * 16 + (lane & 15);
            int k0 = (lane >> 4) * 8;
            short8 o;
#pragma unroll
            for (int j = 0; j < 8; ++j) {
                int k = k0 + j;
                o[j] = f2bf_bits(k < 9 ? W1[k * 512 + col] : 0.f);
            }
            *reinterpret_cast<short8*>(W1frag + (size_t)t * 8) = o;
        }
        return;
    }
    int node = bid * 8 + (threadIdx.x >> 5);
    if (node >= n) return;
    int l = threadIdx.x & 31;
    int slot = l >> 4;        // edge slot 0/1
    int f = l & 15;
    bool act = f < 9;
    float acc = (act && slot == 0) ? xs[node * 9 + f] : 0.f;  // self-loop once
    int e0 = row_ptr[node], e1 = row_ptr[node + 1];
    int e = e0;
    for (; e + 16 <= e1; e += 16) {       // 8 gathers in flight per lane
        int si[8];
        float xv[8];
#pragma unroll
        for (int j = 0; j < 8; ++j) si[j] = csr[e + 2 * j + slot];
#pragma unroll
        for (int j = 0; j < 8; ++j) xv[j] = act ? xs[si[j] * 9 + f] : 0.f;
#pragma unroll
        for (int j = 0; j < 8; ++j) acc += xv[j];
    }
    for (; e + 4 <= e1; e += 4) {         // 2 per slot
        int s0 = csr[e + slot], s1 = csr[e + 2 + slot];
        float x0 = act ? xs[s0 * 9 + f] : 0.f;
        float x1 = act ? xs[s1 * 9 + f] : 0.f;
        acc += x0 + x1;
    }
    for (; e + 2 <= e1; e += 2) {         // 1 per slot
        int s0 = csr[e + slot];
        acc += act ? xs[s0 * 9 + f] : 0.f;
    }
    if (e < e1 && slot == 0) {            // final odd edge
        int s0 = csr[e];
        acc += act ? xs[s0 * 9 + f] : 0.f;
    }
    acc += __shfl_xor(acc, 16);           // merge edge slots
    if (slot == 0) {
        float v = act ? dinv[node] * acc : 0.f;
        __hip_bfloat16* op = aggx_bf + (size_t)node * 32;
        union { __hip_bfloat16 h; short s; } u;
        u.h = __float2bfloat16(v);
        reinterpret_cast<short*>(op)[f] = u.s;
        reinterpret_cast<short*>(op)[16 + f] = 0;
    }
}

// ---------------- Fused layer1-MFMA + layer2 GEMM (r21 best config) ----------------
// Both 16-row tiles of a pair in ONE kt loop (32 rows/wave); 8 bsh (W2)
// ds_read_b128 per kt feed 16 acc-MFMAs.  128 KB LDS W2 stage (best measured).

__global__ __launch_bounds__(512, 2) void k_l12(const __hip_bfloat16* __restrict__ aggx_bf,
                       const __hip_bfloat16* __restrict__ W1frag, const float* __restrict__ b1,
                       const float* __restrict__ W2, const float* __restrict__ dinv,
                       __hip_bfloat16* __restrict__ t2, int n, int npair) {
    __shared__ short bsh[64 * 128 * 8];   // 128 KB: [kb 0..63][c 0..127][j 0..7]
    __shared__ short h1s[8][2][16][40];   // 20 KB: per-wave 2 tiles x 16 rows x 32 cols
    int t = threadIdx.x;

    // Stage all 128 cols of W2 (fp32 -> bf16) into LDS.
    for (int idx = t; idx < 64 * 128; idx += 512) {
        int kb = idx >> 7, c = idx & 127;
        const float* wp = W2 + (size_t)(kb * 8) * 128 + c;
        short8 o;
#pragma unroll
        for (int j = 0; j < 8; ++j) o[j] = f2bf_bits(wp[j * 128]);
        *reinterpret_cast<short8*>(bsh + (size_t)idx * 8) = o;
    }
    __syncthreads();

    int wid = t >> 6, lane = t & 63;
    int pair = blockIdx.x * 8 + wid;
    if (pair >= npair) return;
    int r = lane & 15, quad = lane >> 4;
    short (*hs0)[40] = h1s[wid][0];
    short (*hs1)[40] = h1s[wid][1];

    int m0 = pair << 5;
    short8 aagg0 = *reinterpret_cast<const short8*>(
        aggx_bf + (size_t)(m0 + r) * 32 + quad * 8);
    short8 aagg1 = *reinterpret_cast<const short8*>(
        aggx_bf + (size_t)(m0 + 16 + r) * 32 + quad * 8);

    float4v acc0[8], acc1[8];
#pragma unroll
    for (int cg = 0; cg < 8; ++cg) {
        acc0[cg] = (float4v){0, 0, 0, 0};
        acc1[cg] = (float4v){0, 0, 0, 0};
    }

    for (int kt = 0; kt < 16; ++kt) {
        short8 bf0 = *reinterpret_cast<const short8*>(
            W1frag + ((size_t)(2 * kt) * 64 + lane) * 8);
        short8 bf1 = *reinterpret_cast<const short8*>(
            W1frag + ((size_t)(2 * kt + 1) * 64 + lane) * 8);
        float4v c00 = __builtin_amdgcn_mfma_f32_16x16x32_bf16(
            aagg0, bf0, (float4v){0, 0, 0, 0}, 0, 0, 0);
        float4v c01 = __builtin_amdgcn_mfma_f32_16x16x32_bf16(
            aagg0, bf1, (float4v){0, 0, 0, 0}, 0, 0, 0);
        float4v c10 = __builtin_amdgcn_mfma_f32_16x16x32_bf16(
            aagg1, bf0, (float4v){0, 0, 0, 0}, 0, 0, 0);
        float4v c11 = __builtin_amdgcn_mfma_f32_16x16x32_bf16(
            aagg1, bf1, (float4v){0, 0, 0, 0}, 0, 0, 0);
        float bb0 = b1[kt * 32 + r];
        float bb1 = b1[kt * 32 + 16 + r];
#pragma unroll
        for (int i = 0; i < 4; ++i) {
            int row = quad * 4 + i;
            hs0[row][r]      = f2bf_bits(fmaxf(c00[i] + bb0, 0.f));
            hs0[row][16 + r] = f2bf_bits(fmaxf(c01[i] + bb1, 0.f));
            hs1[row][r]      = f2bf_bits(fmaxf(c10[i] + bb0, 0.f));
            hs1[row][16 + r] = f2bf_bits(fmaxf(c11[i] + bb1, 0.f));
        }
        short8 am0 = *reinterpret_cast<const short8*>(&hs0[r][quad * 8]);
        short8 am1 = *reinterpret_cast<const short8*>(&hs1[r][quad * 8]);
#pragma unroll
        for (int cg = 0; cg < 8; ++cg) {
            short8 b = *reinterpret_cast<const short8*>(
                bsh + (size_t)(((kt * 4 + quad) * 128) + cg * 16 + r) * 8);
            acc0[cg] = __builtin_amdgcn_mfma_f32_16x16x32_bf16(am0, b, acc0[cg], 0, 0, 0);
            acc1[cg] = __builtin_amdgcn_mfma_f32_16x16x32_bf16(am1, b, acc1[cg], 0, 0, 0);
        }
    }

#pragma unroll
    for (int i = 0; i < 4; ++i) {
        int node0 = m0 + quad * 4 + i;
        if (node0 < n) {
            float di = dinv[node0];
            __hip_bfloat16* op = t2 + (size_t)node0 * 128 + r;
#pragma unroll
            for (int cg = 0; cg < 8; ++cg)
                op[cg * 16] = __float2bfloat16(di * acc0[cg][i]);
        }
        int node1 = m0 + 16 + quad * 4 + i;
        if (node1 < n) {
            float di = dinv[node1];
            __hip_bfloat16* op = t2 + (size_t)node1 * 128 + r;
#pragma unroll
            for (int cg = 0; cg < 8; ++cg)
                op[cg * 16] = __float2bfloat16(di * acc1[cg][i]);
        }
    }
}

// ---------------- Layer 2 aggregate + fused layer-3 matmul (r20 proven) ----------------

__global__ __launch_bounds__(256) void k_agg2(const uint* __restrict__ t2u,
                       const float* __restrict__ dinv,
                       const int* __restrict__ row_ptr, const int* __restrict__ csr,
                       const float* __restrict__ b2, const float* __restrict__ W3,
                       float2* __restrict__ t3, int n) {
    int node = blockIdx.x * 4 + (threadIdx.x >> 6);
    if (node >= n) return;
    int lane = threadIdx.x & 63;
    int half = lane >> 5;    // 0: even edges, 1: odd edges
    int cl = lane & 31;      // channel chunk: channels 4*cl .. 4*cl+3
    const uint2* t2v = reinterpret_cast<const uint2*>(t2u);

    float a0 = 0.f, a1 = 0.f, a2 = 0.f, a3 = 0.f;
    if (half == 0) {  // self row (t2' = dinv*t2), added once
        uint2 sv = t2v[(size_t)node * 32 + cl];
        float2 pa = up_bf2(sv.x), pb = up_bf2(sv.y);
        a0 = pa.x; a1 = pa.y; a2 = pb.x; a3 = pb.y;
    }

    int e0 = row_ptr[node], e1 = row_ptr[node + 1];
    int eb = e0;
    for (; eb + 16 <= e1; eb += 16) {  // 8 edges per half in flight
        int si[8];
        uint2 ri[8];
#pragma unroll
        for (int j = 0; j < 8; ++j) si[j] = csr[eb + half + 2 * j];
#pragma unroll
        for (int j = 0; j < 8; ++j) ri[j] = t2v[(size_t)si[j] * 32 + cl];
#pragma unroll
        for (int j = 0; j < 8; ++j) {
            float2 qa = up_bf2(ri[j].x), qb = up_bf2(ri[j].y);
            a0 += qa.x; a1 += qa.y; a2 += qb.x; a3 += qb.y;
        }
    }
    for (; eb + 4 <= e1; eb += 4) {  // 2 edges per half
        int s0 = csr[eb + half], s1 = csr[eb + half + 2];
        uint2 r0 = t2v[(size_t)s0 * 32 + cl];
        uint2 r1 = t2v[(size_t)s1 * 32 + cl];
        float2 qa = up_bf2(r0.x), qb = up_bf2(r0.y);
        float2 qc = up_bf2(r1.x), qd = up_bf2(r1.y);
        a0 += qa.x + qc.x; a1 += qa.y + qc.y;
        a2 += qb.x + qd.x; a3 += qb.y + qd.y;
    }
    for (int e = eb + half; e < e1; e += 2) {  // tail 0-3 edges
        uint2 rv = t2v[(size_t)csr[e] * 32 + cl];
        float2 qa = up_bf2(rv.x), qb = up_bf2(rv.y);
        a0 += qa.x; a1 += qa.y; a2 += qb.x; a3 += qb.y;
    }

    // merge even/odd halves: lanes l and l^32 hold same channel chunk
    a0 += __shfl_xor(a0, 32);
    a1 += __shfl_xor(a1, 32);
    a2 += __shfl_xor(a2, 32);
    a3 += __shfl_xor(a3, 32);

    float di = dinv[node];
    float4 bb = *reinterpret_cast<const float4*>(b2 + 4 * cl);
    float h0 = fmaxf(di * a0 + bb.x, 0.f);
    float h1v = fmaxf(di * a1 + bb.y, 0.f);
    float h2 = fmaxf(di * a2 + bb.z, 0.f);
    float h3 = fmaxf(di * a3 + bb.w, 0.f);
    float4 wlo = *reinterpret_cast<const float4*>(W3 + 8 * cl);      // rows 4cl, 4cl+1
    float4 whi = *reinterpret_cast<const float4*>(W3 + 8 * cl + 4);  // rows 4cl+2, 4cl+3
    float c0 = h0 * wlo.x + h1v * wlo.z + h2 * whi.x + h3 * whi.z;
    float c1 = h0 * wlo.y + h1v * wlo.w + h2 * whi.y + h3 * whi.w;
#pragma unroll
    for (int off = 16; off; off >>= 1) {  // reduce within each 32-lane group
        c0 += __shfl_xor(c0, off);
        c1 += __shfl_xor(c1, off);
    }
    if (lane == 0) t3[node] = make_float2(di * c0, di * c1);  // prescaled
}

// ---------------- Layer 3 aggregate + log_softmax ----------------

__global__ void k_agg3(const float2* __restrict__ t3, const float* __restrict__ dinv,
                       const int* __restrict__ row_ptr, const int* __restrict__ csr,
                       const float* __restrict__ b3, float2* __restrict__ outv, int n) {
    int node = blockIdx.x * blockDim.x + threadIdx.x;
    if (node >= n) return;
    float2 s = t3[node];  // self (t3' = dinv*t3)
    float a0 = s.x, a1 = s.y;
    int e0 = row_ptr[node], e1 = row_ptr[node + 1];
    int e = e0;
    for (; e + 4 <= e1; e += 4) {
        int s0 = csr[e], s1 = csr[e + 1], s2 = csr[e + 2], s3 = csr[e + 3];
        float2 q0 = t3[s0], q1 = t3[s1], q2 = t3[s2], q3 = t3[s3];
        a0 += q0.x + q1.x + q2.x + q3.x;
        a1 += q0.y + q1.y + q2.y + q3.y;
    }
    for (; e < e1; ++e) {
        float2 q0 = t3[csr[e]];
        a0 += q0.x;
        a1 += q0.y;
    }
    float di = dinv[node];
    float z0 = di * a0 + b3[0];
    float z1 = di * a1 + b3[1];
    float m = fmaxf(z0, z1);
    float lse = m + logf(expf(z0 - m) + expf(z1 - m));
    outv[node] = make_float2(z0 - lse, z1 - lse);
}

// ---------------- launch ----------------

extern "C" void kernel_launch(void* const* d_in, const int* in_sizes, int n_in,
                              void* d_out, int out_size, void* d_ws, size_t ws_size,
                              hipStream_t stream) {
    const float* x  = (const float*)d_in[0];
    const float* W1 = (const float*)d_in[1];
    const float* b1 = (const float*)d_in[2];
    const float* W2 = (const float*)d_in[3];
    const float* b2 = (const float*)d_in[4];
    const float* W3 = (const float*)d_in[5];
    const float* b3 = (const float*)d_in[6];
    const int* edges = (const int*)d_in[7];

    int n = in_sizes[0] / 9;
    int E = in_sizes[7] / 2;
    const int* src = edges;
    const int* dst = edges + E;

    char* p = (char*)d_ws;
    auto alloc = [&](size_t bytes) {
        char* q = p;
        p += (bytes + 511) & ~(size_t)511;
        return q;
    };
    float* dinv       = (float*)alloc((size_t)n * 4);
    int*   row_ptr    = (int*)alloc((size_t)(n + 1) * 4);
    int*   csr        = (int*)alloc((size_t)E * 4);
    int*   histBlk    = (int*)alloc((size_t)256 * NBLK * 4);
    int*   baseBlk    = (int*)alloc((size_t)256 * NBLK * 4);
    int*   btot       = (int*)alloc(256 * 4);
    int*   bucketBase = (int*)alloc(256 * 4);
    uint*  binned     = (uint*)alloc((size_t)E * 4);
    float* xs         = (float*)alloc((size_t)n * 9 * 4);
    __hip_bfloat16* aggx_bf = (__hip_bfloat16*)alloc((size_t)(n + 64) * 32 * 2);
    __hip_bfloat16* W1frag  = (__hip_bfloat16*)alloc((size_t)32 * 64 * 8 * 2);
    __hip_bfloat16* t2 = (__hip_bfloat16*)alloc((size_t)n * 128 * 2);
    float2* t3 = (float2*)alloc((size_t)n * 8);

    const int B = 256;
    int shift = 8;  // packed binned requires shift==8 (dst_local 8b) and n < 2^24
    int nbuck = ((n - 1) >> shift) + 1;
    int chunk = (E + NBLK - 1) / NBLK;

    k_hist<<<NBLK, B, 0, stream>>>(dst, E, chunk, shift, nbuck, histBlk);
    k_btot<<<nbuck, B, 0, stream>>>(histBlk, btot);
    k_bscan<<<nbuck, B, 0, stream>>>(histBlk, btot, nbuck, baseBlk, bucketBase);
    k_scatterbin<<<NBLK, B, 0, stream>>>(src, dst, E, chunk, shift, nbuck, baseBlk, binned);
    k_csrbuild<<<nbuck, B, 0, stream>>>(binned, bucketBase, x, E, shift, n, nbuck,
                                        row_ptr, dinv, xs, csr);

    int nagg = (n + 7) / 8;                   // 6250 agg1 blocks (+8 W1frag)
    k_agg1w<<<nagg + 8, B, 0, stream>>>(xs, dinv, row_ptr, csr, W1,
                                        aggx_bf, W1frag, n, nagg);

    int ntile = (n + 15) / 16;                // 3125
    int npair = (ntile + 1) / 2;              // 1563 wave-tasks (32 rows each)
    k_l12<<<(npair + 7) / 8, 512, 0, stream>>>(aggx_bf, W1frag, b1, W2, dinv, t2, n, npair);
    k_agg2<<<(n + 3) / 4, 256, 0, stream>>>((const uint*)t2, dinv, row_ptr, csr, b2, W3, t3, n);

    k_agg3<<<(n + B - 1) / B, B, 0, stream>>>(t3, dinv, row_ptr, csr, b3, (float2*)d_out, n);
}